// Round 1
// baseline (9318.011 us; speedup 1.0000x reference)
//
#include <hip/hip_runtime.h>
#include <cstdint>
#include <cstddef>

#define HH      100
#define G4      400
#define BTOT    8192
#define TSTEPS  512
#define NOPS    5
#define ROWS    32
#define NBLK    256
#define BLOCK   832            // 13 waves
#define CHUNK_K 10
#define NCHUNK  10
#define CHUNK_F (CHUNK_K*G4)   // 4000 floats
#define CHUNK_BYTES (CHUNK_F*4) // 16000
#define HSTR    36             // h_lds row stride (words), 16B-aligned, conflict-free
#define TANHC   1.5f
#define EPSF    1e-9f

// precomputed weights live in device globals (no d_ws dependency)
__device__ float d_Whp[HH*G4];   // W_h permuted: [k][j][g] = W_h[k][g*100+j]
__device__ float d_Wxp[HH*G4];   // W_x permuted likewise
__device__ float d_Epg[6*G4];    // E[e][j][g] = sum_k emb[e][k]*W_x[k][g*100+j]

__device__ __forceinline__ float sigf(float x){ return 1.0f/(1.0f + expf(-x)); }

__device__ __forceinline__ void async16(const float* g, float* l){
  __builtin_amdgcn_global_load_lds(
      (const __attribute__((address_space(1))) unsigned int*)g,
      (__attribute__((address_space(3))) unsigned int*)l,
      16, 0, 0);
}

// stage one 16000B W-chunk global->LDS; every wave issues <=2 global_load_lds
__device__ __forceinline__ void issue_chunk(const float* gsrc, float* lbase,
                                            int wave, int lane){
  {
    const int ofsw = wave << 8;                 // wave*1024 bytes in words
    async16(gsrc + ofsw + lane*4, lbase + ofsw + lane*4);
  }
  {
    const int ofsb = 13312 + (wave << 10);      // bytes
    if (ofsb < CHUNK_BYTES){                    // wave-uniform branch
      const int rem = CHUNK_BYTES - ofsb;
      if ((lane << 4) < rem){                   // exec-mask partial tail
        const int ofsw = ofsb >> 2;
        async16(gsrc + ofsw + lane*4, lbase + ofsw + lane*4);
      }
    }
  }
}

__global__ void setup_permute(const float* __restrict__ Wh, const float* __restrict__ Wx){
  int idx = blockIdx.x*blockDim.x + threadIdx.x;
  if (idx >= HH*G4) return;
  int k = idx / G4, rem = idx - k*G4, j = rem >> 2, g = rem & 3;
  d_Whp[idx] = Wh[k*G4 + g*HH + j];
  d_Wxp[idx] = Wx[k*G4 + g*HH + j];
}

__global__ void setup_emb(const float* __restrict__ emb, const float* __restrict__ Wx){
  int idx = blockIdx.x*blockDim.x + threadIdx.x;
  if (idx >= 6*G4) return;
  int e = idx / G4, rem = idx - e*G4, j = rem >> 2, g = rem & 3;
  float s = 0.f;
  for (int k = 0; k < HH; ++k) s = fmaf(emb[e*HH + k], Wx[k*G4 + g*HH + j], s);
  d_Epg[idx] = s;
}

__global__ __launch_bounds__(BLOCK) void rnn_main(
    const float* __restrict__ x0, const float* __restrict__ Wops,
    const float* __restrict__ u, float* __restrict__ out)
{
  __shared__ __align__(16) float Wc[2][CHUNK_F];      // 32000 B (double buffer)
  __shared__ __align__(16) float h_lds[HH*HSTR];      // 14400 B, h[k][r]
  __shared__ __align__(16) float Ep_lds[6*G4];        //  9600 B
  __shared__ __align__(16) float Wops_lds[HH*NOPS];   //  2000 B
  __shared__ __align__(16) float red_lds[ROWS*NOPS*5];//  3200 B
  __shared__ int op_lds[ROWS];                        //   128 B

  const int tid  = threadIdx.x;
  const int wave = tid >> 6;
  const int lane = tid & 63;
  const int j    = wave*8 + (lane & 7);   // gate-column group this lane owns
  const int jc   = (j < HH) ? j : (HH-1); // clamp; junk lanes never used
  const int r4   = (lane >> 3) * 4;       // first of 4 rows this lane owns
  const int row0 = blockIdx.x * ROWS;

  // prologue staging
  for (int i = tid; i < 6*G4; i += BLOCK) Ep_lds[i] = d_Epg[i];
  for (int i = tid; i < HH*NOPS; i += BLOCK) Wops_lds[i] = Wops[i];
  for (int i = tid; i < ROWS*HH; i += BLOCK){
    int r = i / HH, k = i - r*HH;
    h_lds[k*HSTR + r] = x0[(size_t)(row0 + r)*HH + k];   // step 0 "h" = x0
  }
  issue_chunk(d_Wxp, &Wc[0][0], wave, lane);             // prefetch step-0 chunk 0

  float c_st[4] = {0.f,0.f,0.f,0.f};
  float lp_acc = 0.f, ent_acc = 0.f;
  const float* wsrc = d_Wxp;

  for (int t = 0; t < TSTEPS; ++t){
    float acc[4][4];                                     // [gate][row]
    if (t == 0){
      #pragma unroll
      for (int g = 0; g < 4; ++g)
        #pragma unroll
        for (int rr = 0; rr < 4; ++rr) acc[g][rr] = 0.f;
    } else {
      #pragma unroll
      for (int rr = 0; rr < 4; ++rr){                    // z init = emb[op] @ W_x
        int op = op_lds[r4 + rr];
        float4 e = *(const float4*)&Ep_lds[(op*HH + jc)*4];
        acc[0][rr] = e.x; acc[1][rr] = e.y; acc[2][rr] = e.z; acc[3][rr] = e.w;
      }
    }
    float uv[NOPS];
    if (tid < ROWS){                                     // prefetch gumbel inputs
      const float* up = u + ((size_t)t*BTOT + row0 + tid)*NOPS;
      #pragma unroll
      for (int o = 0; o < NOPS; ++o) uv[o] = up[o];
    }
    // K-loop: z += h @ W (W streamed L2->LDS, double buffered)
    for (int c = 0; c < NCHUNK; ++c){
      __syncthreads();  // drains vmcnt(0): chunk c ready; all waves past chunk c-1
      if (c+1 < NCHUNK) issue_chunk(wsrc + (size_t)(c+1)*CHUNK_F, &Wc[(c+1)&1][0], wave, lane);
      const float* wrow = &Wc[c&1][jc*4];
      const float* hrow = &h_lds[(c*CHUNK_K)*HSTR + r4];
      #pragma unroll
      for (int kk = 0; kk < CHUNK_K; ++kk){
        float4 wf = *(const float4*)(wrow + kk*G4);      // 4 gates of col j (bcast x8)
        float4 hf = *(const float4*)(hrow + kk*HSTR);    // 4 rows (bcast x8)
        float wv[4] = {wf.x, wf.y, wf.z, wf.w};
        float hv[4] = {hf.x, hf.y, hf.z, hf.w};
        #pragma unroll
        for (int g = 0; g < 4; ++g)
          #pragma unroll
          for (int rr = 0; rr < 4; ++rr)
            acc[g][rr] = fmaf(wv[g], hv[rr], acc[g][rr]);
      }
    }
    __syncthreads();                                     // all reads of h_lds / Wc done
    issue_chunk(d_Whp, &Wc[0][0], wave, lane);           // prefetch next step chunk 0
    wsrc = d_Whp;

    // LSTM elementwise (registers), h_new -> LDS
    if (j < HH){
      float hnew[4];
      #pragma unroll
      for (int rr = 0; rr < 4; ++rr){
        float zi = acc[0][rr], zf = acc[1][rr], zc = acc[2][rr], zo = acc[3][rr];
        float cn = sigf(zf)*c_st[rr] + sigf(zi)*tanhf(zc);
        c_st[rr] = cn;
        hnew[rr] = sigf(zo)*tanhf(cn);
      }
      float4 hw; hw.x=hnew[0]; hw.y=hnew[1]; hw.z=hnew[2]; hw.w=hnew[3];
      *(float4*)&h_lds[j*HSTR + r4] = hw;
    }
    __syncthreads();

    // logits partials: thread=(r,o,jq) sums 20 j's
    if (tid < ROWS*NOPS*5){
      int r = tid/25, rem = tid - r*25, o = rem/5, jq = rem - o*5;
      float s = 0.f;
      #pragma unroll 4
      for (int jj = 0; jj < 20; ++jj){
        int j2 = jq*20 + jj;
        s = fmaf(h_lds[j2*HSTR + r], Wops_lds[j2*NOPS + o], s);
      }
      red_lds[tid] = s;
    }
    __syncthreads();

    // per-row: gumbel argmax, log-softmax, accumulate
    if (tid < ROWS){
      int r = tid;
      float l[NOPS];
      #pragma unroll
      for (int o = 0; o < NOPS; ++o){
        const float* rp = &red_lds[r*25 + o*5];
        float s = (((rp[0]+rp[1])+rp[2])+rp[3])+rp[4];
        l[o] = TANHC * tanhf(s);
      }
      int op = 0; float best = -1e30f;
      #pragma unroll
      for (int o = 0; o < NOPS; ++o){
        float gn = -logf(-logf(uv[o] + EPSF) + EPSF);
        float v = l[o] + gn;
        if (v > best){ best = v; op = o; }               // strict >: first-max tie-break
      }
      float m = l[0];
      #pragma unroll
      for (int o = 1; o < NOPS; ++o) m = fmaxf(m, l[o]);
      float se = 0.f;
      #pragma unroll
      for (int o = 0; o < NOPS; ++o) se += expf(l[o] - m);
      float lse = m + logf(se);
      float cur = lse - l[op];
      lp_acc  += cur;
      ent_acc += cur * expf(-cur);
      op_lds[r] = op;
      out[2*BTOT + (size_t)t*BTOT + row0 + r] = (float)op;
    }
    __syncthreads();                                     // op_lds ready for next step
  }

  if (tid < ROWS){
    out[row0 + tid]        = lp_acc;
    out[BTOT + row0 + tid] = ent_acc;
  }
}

extern "C" void kernel_launch(void* const* d_in, const int* in_sizes, int n_in,
                              void* d_out, int out_size, void* d_ws, size_t ws_size,
                              hipStream_t stream) {
  const float* x0   = (const float*)d_in[0];
  const float* Wx   = (const float*)d_in[1];
  const float* Wh   = (const float*)d_in[2];
  const float* Wops = (const float*)d_in[3];
  const float* emb  = (const float*)d_in[4];
  const float* u    = (const float*)d_in[5];
  (void)d_ws; (void)ws_size; (void)in_sizes; (void)n_in;

  setup_permute<<<(HH*G4 + 255)/256, 256, 0, stream>>>(Wh, Wx);
  setup_emb<<<(6*G4 + 255)/256, 256, 0, stream>>>(emb, Wx);
  rnn_main<<<NBLK, BLOCK, 0, stream>>>(x0, Wops, u, (float*)d_out);
}